// Round 5
// baseline (105.091 us; speedup 1.0000x reference)
//
#include <hip/hip_runtime.h>

#define BB 2
#define TT 512
#define HH 256

// 2*log2(e): exp(2x) = 2^(C*x)
#define C2LOG2E 2.8853900817779268f

// ---------------------------------------------------------------------------
// Kernel 1: projections + exponential transform.
// Y[bt,o] = exp2(C * sum_h X[bt,h] * W[o,h])
// Block = 8 rows x 64 outs; 256 threads = 64 o x 4 row-subgroups (2 rows each).
// Grid = 2 * (B*T/8) * (H/64) = 1024 blocks.
// ---------------------------------------------------------------------------
__global__ __launch_bounds__(256) void proj_kernel(
    const float* __restrict__ Q, const float* __restrict__ K,
    const float* __restrict__ Wq, const float* __restrict__ Wk,
    float* __restrict__ Eq, float* __restrict__ Ek)
{
    int gid = blockIdx.x;
    bool isK = (gid >= 512);
    int g = isK ? gid - 512 : gid;
    int rowgrp = g >> 2;            // 0..127
    int ogrp = g & 3;               // 0..3
    int bt0 = rowgrp * 8;
    int o0 = ogrp * 64;

    const float* X = isK ? K : Q;
    const float* W = isK ? Wk : Wq;
    float* Y = isK ? Ek : Eq;

    int o  = threadIdx.x & 63;
    int rs = threadIdx.x >> 6;      // 0..3, wave index
    int r0 = bt0 + rs * 2;

    const float4* w4p  = reinterpret_cast<const float4*>(W + (o0 + o) * HH);
    const float4* x4p0 = reinterpret_cast<const float4*>(X + r0 * HH);
    const float4* x4p1 = reinterpret_cast<const float4*>(X + (r0 + 1) * HH);

    float acc0 = 0.f, acc1 = 0.f;
#pragma unroll 4
    for (int h4 = 0; h4 < HH / 4; ++h4) {
        float4 w4 = w4p[h4];
        float4 xa = x4p0[h4];       // wave-uniform address
        float4 xb = x4p1[h4];       // wave-uniform address
        acc0 += xa.x * w4.x + xa.y * w4.y + xa.z * w4.z + xa.w * w4.w;
        acc1 += xb.x * w4.x + xb.y * w4.y + xb.z * w4.z + xb.w * w4.w;
    }
    Y[r0 * HH + o0 + o]       = __builtin_amdgcn_exp2f(acc0 * C2LOG2E);
    Y[(r0 + 1) * HH + o0 + o] = __builtin_amdgcn_exp2f(acc1 * C2LOG2E);
}

// ---------------------------------------------------------------------------
// Kernel 2: fused scores + causal softmax + context. One block per (b,t).
// score'(t,s) = sum_h v2[h] * rcp(Eq[t,h]*Ek[s,h] + 1),  v2 = -2v
// Block->t permuted so blocks idx and idx+256 have work summing to 511.
// ---------------------------------------------------------------------------
__global__ __launch_bounds__(256) void attn_kernel(
    const float* __restrict__ Eq, const float* __restrict__ Ek,
    const float* __restrict__ Kraw, const float* __restrict__ v,
    float* __restrict__ ctx, float* __restrict__ alpha)
{
    int bt = blockIdx.x;            // 0 .. B*T-1
    int b = bt / TT;
    int idx = bt % TT;
    int t = (idx < 256) ? idx : 767 - idx;   // bijective, load-balancing
    int btr = b * TT + t;
    int tid = threadIdx.x;          // 0..255

    __shared__ float eq_sh[HH];
    __shared__ float v2_sh[HH];
    __shared__ float al_sh[TT];
    __shared__ float red[4];
    __shared__ float4 cred[4][64];

    eq_sh[tid] = Eq[btr * HH + tid];
    v2_sh[tid] = -2.0f * v[tid];
    __syncthreads();

    const float4* q4p = reinterpret_cast<const float4*>(eq_sh);
    const float4* v4p = reinterpret_cast<const float4*>(v2_sh);

    // ---- scores: s0 = tid (always <= t when t>=256), s1 = tid+256 ----
    float sc0 = -3.0e38f, sc1 = -3.0e38f;
    const float4* ekbase = reinterpret_cast<const float4*>(Ek + b * TT * HH);
    if (t >= 256) {
        // merged dual-stream loop: 2 independent global load chains
        const float4* ek0 = ekbase + tid * (HH / 4);
        const float4* ek1 = ekbase + (tid + 256) * (HH / 4);
        float a0 = 0.f, a1 = 0.f;
#pragma unroll 2
        for (int h4 = 0; h4 < HH / 4; ++h4) {
            float4 ea = ek0[h4];
            float4 eb = ek1[h4];
            float4 q4 = q4p[h4];
            float4 vv = v4p[h4];
            float r0 = __builtin_amdgcn_rcpf(__builtin_fmaf(q4.x, ea.x, 1.0f));
            float r1 = __builtin_amdgcn_rcpf(__builtin_fmaf(q4.y, ea.y, 1.0f));
            float r2 = __builtin_amdgcn_rcpf(__builtin_fmaf(q4.z, ea.z, 1.0f));
            float r3 = __builtin_amdgcn_rcpf(__builtin_fmaf(q4.w, ea.w, 1.0f));
            float u0 = __builtin_amdgcn_rcpf(__builtin_fmaf(q4.x, eb.x, 1.0f));
            float u1 = __builtin_amdgcn_rcpf(__builtin_fmaf(q4.y, eb.y, 1.0f));
            float u2 = __builtin_amdgcn_rcpf(__builtin_fmaf(q4.z, eb.z, 1.0f));
            float u3 = __builtin_amdgcn_rcpf(__builtin_fmaf(q4.w, eb.w, 1.0f));
            a0 = __builtin_fmaf(vv.x, r0, a0);
            a0 = __builtin_fmaf(vv.y, r1, a0);
            a0 = __builtin_fmaf(vv.z, r2, a0);
            a0 = __builtin_fmaf(vv.w, r3, a0);
            a1 = __builtin_fmaf(vv.x, u0, a1);
            a1 = __builtin_fmaf(vv.y, u1, a1);
            a1 = __builtin_fmaf(vv.z, u2, a1);
            a1 = __builtin_fmaf(vv.w, u3, a1);
        }
        sc0 = a0;
        sc1 = (tid + 256 <= t) ? a1 : -3.0e38f;
    } else {
        if (tid <= t) {
            const float4* ek0 = ekbase + tid * (HH / 4);
            float a0 = 0.f;
#pragma unroll 4
            for (int h4 = 0; h4 < HH / 4; ++h4) {
                float4 ea = ek0[h4];
                float4 q4 = q4p[h4];
                float4 vv = v4p[h4];
                float r0 = __builtin_amdgcn_rcpf(__builtin_fmaf(q4.x, ea.x, 1.0f));
                float r1 = __builtin_amdgcn_rcpf(__builtin_fmaf(q4.y, ea.y, 1.0f));
                float r2 = __builtin_amdgcn_rcpf(__builtin_fmaf(q4.z, ea.z, 1.0f));
                float r3 = __builtin_amdgcn_rcpf(__builtin_fmaf(q4.w, ea.w, 1.0f));
                a0 = __builtin_fmaf(vv.x, r0, a0);
                a0 = __builtin_fmaf(vv.y, r1, a0);
                a0 = __builtin_fmaf(vv.z, r2, a0);
                a0 = __builtin_fmaf(vv.w, r3, a0);
            }
            sc0 = a0;
        }
    }

    // ---- block max over valid scores ----
    float m = fmaxf(sc0, sc1);
#pragma unroll
    for (int off = 32; off > 0; off >>= 1)
        m = fmaxf(m, __shfl_xor(m, off));
    int wid = tid >> 6;
    if ((tid & 63) == 0) red[wid] = m;
    __syncthreads();
    m = fmaxf(fmaxf(red[0], red[1]), fmaxf(red[2], red[3]));

    // ---- exp + block sum ----
    const float LOG2E = 1.4426950408889634f;
    float e0 = (tid       <= t) ? __builtin_amdgcn_exp2f((sc0 - m) * LOG2E) : 0.f;
    float e1 = (tid + 256 <= t) ? __builtin_amdgcn_exp2f((sc1 - m) * LOG2E) : 0.f;
    float ssum = e0 + e1;
#pragma unroll
    for (int off = 32; off > 0; off >>= 1)
        ssum += __shfl_xor(ssum, off);
    __syncthreads();           // everyone done reading red[]
    if ((tid & 63) == 0) red[wid] = ssum;
    __syncthreads();
    float denom = red[0] + red[1] + red[2] + red[3];
    float inv = 1.0f / denom;

    float a0 = e0 * inv;
    float a1 = e1 * inv;
    al_sh[tid]       = a0;
    al_sh[tid + 256] = a1;
    alpha[btr * TT + tid]       = a0;
    alpha[btr * TT + tid + 256] = a1;
    __syncthreads();

    // ---- context: thread = (h-group hc, s-group sg) ----
    // hc in [0,64): handles channels 4hc..4hc+3; sg in [0,4): s = sg, sg+4, ...
    int hc = tid & 63;
    int sg = tid >> 6;
    const float4* kb4 = reinterpret_cast<const float4*>(Kraw + b * TT * HH) + hc;
    float4 acc4 = {0.f, 0.f, 0.f, 0.f};
#pragma unroll 2
    for (int s = sg; s <= t; s += 4) {
        float4 k4 = kb4[s * 64];            // coalesced 1KB/wave
        float  al = al_sh[s];               // wave-uniform broadcast
        acc4.x = __builtin_fmaf(al, k4.x, acc4.x);
        acc4.y = __builtin_fmaf(al, k4.y, acc4.y);
        acc4.z = __builtin_fmaf(al, k4.z, acc4.z);
        acc4.w = __builtin_fmaf(al, k4.w, acc4.w);
    }
    cred[sg][hc] = acc4;
    __syncthreads();
    if (sg == 0) {
        float4 c0 = cred[0][hc], c1 = cred[1][hc], c2 = cred[2][hc], c3 = cred[3][hc];
        float4 out;
        out.x = (c0.x + c1.x) + (c2.x + c3.x);
        out.y = (c0.y + c1.y) + (c2.y + c3.y);
        out.z = (c0.z + c1.z) + (c2.z + c3.z);
        out.w = (c0.w + c1.w) + (c2.w + c3.w);
        reinterpret_cast<float4*>(ctx + btr * HH)[hc] = out;
    }
}

extern "C" void kernel_launch(void* const* d_in, const int* in_sizes, int n_in,
                              void* d_out, int out_size, void* d_ws, size_t ws_size,
                              hipStream_t stream) {
    const float* Q  = (const float*)d_in[0];
    const float* K  = (const float*)d_in[1];
    const float* Wq = (const float*)d_in[2];
    const float* Wk = (const float*)d_in[3];
    const float* v  = (const float*)d_in[4];

    float* ctx   = (float*)d_out;                      // B*T*H floats
    float* alpha = (float*)d_out + BB * TT * HH;       // B*T*T floats

    float* Eq = (float*)d_ws;                          // B*T*H
    float* Ek = Eq + BB * TT * HH;                     // B*T*H

    proj_kernel<<<1024, 256, 0, stream>>>(Q, K, Wq, Wk, Eq, Ek);
    attn_kernel<<<BB * TT, 256, 0, stream>>>(Eq, Ek, K, v, ctx, alpha);
}

// Round 6
// 38.848 us; speedup vs baseline: 2.7052x; 2.7052x over previous
//
#include <hip/hip_runtime.h>

#define BB 2
#define TT 512
#define HH 256
#define NBT (BB * TT)

// 2*log2(e): exp(2x) = 2^(C*x)
#define C2LOG2E 2.8853900817779268f

// ---------------------------------------------------------------------------
// Kernel 1: projections + exponential transform. 8 rows/block, thread = o.
// Q-half writes Eq[bt][o] row-major (attn loads it broadcast from LDS).
// K-half writes EkT packed-transposed: float4 slot [h4][bt] so attn's
// thread=s reads are lane-contiguous (1KB/wave coalesced).
// ---------------------------------------------------------------------------
__global__ __launch_bounds__(256) void proj_kernel(
    const float* __restrict__ Q, const float* __restrict__ K,
    const float* __restrict__ Wq, const float* __restrict__ Wk,
    float* __restrict__ Eq, float* __restrict__ EkT)
{
    const int ROWS = 8;
    int grp = blockIdx.x;
    const int nQ = NBT / ROWS;          // 128
    bool isK = (grp >= nQ);
    int bt0 = (isK ? grp - nQ : grp) * ROWS;
    const float* X = isK ? K : Q;
    const float* W = isK ? Wk : Wq;

    int o = threadIdx.x;
    const float4* w4p = reinterpret_cast<const float4*>(W + o * HH);
    const float4* x4p = reinterpret_cast<const float4*>(X + bt0 * HH);

    float acc[ROWS] = {0.f, 0.f, 0.f, 0.f, 0.f, 0.f, 0.f, 0.f};
#pragma unroll 2
    for (int h4 = 0; h4 < HH / 4; ++h4) {
        float4 w4 = w4p[h4];
#pragma unroll
        for (int r = 0; r < ROWS; ++r) {
            float4 x4 = x4p[r * (HH / 4) + h4];   // wave-uniform address
            acc[r] += x4.x * w4.x + x4.y * w4.y + x4.z * w4.z + x4.w * w4.w;
        }
    }
    if (!isK) {
#pragma unroll
        for (int r = 0; r < ROWS; ++r)
            Eq[(bt0 + r) * HH + o] = __builtin_amdgcn_exp2f(acc[r] * C2LOG2E);
    } else {
        int h4 = o >> 2, c = o & 3;
#pragma unroll
        for (int r = 0; r < ROWS; ++r)
            EkT[(h4 * NBT + bt0 + r) * 4 + c] = __builtin_amdgcn_exp2f(acc[r] * C2LOG2E);
    }
}

// ---------------------------------------------------------------------------
// Kernel 2: fused scores + causal softmax + context. One block per (b,t),
// 512 threads (8 waves -> 8 waves/SIMD occupancy).
// score'(t,s) = sum_h v2[h] * rcp(Eq[t,h]*Ek[s,h] + 1),  v2 = -2v
// Block->t permuted so blocks idx and idx+256 have work summing to 511.
// ---------------------------------------------------------------------------
__global__ __launch_bounds__(512, 8) void attn_kernel(
    const float* __restrict__ Eq, const float* __restrict__ EkT,
    const float* __restrict__ Kraw, const float* __restrict__ v,
    float* __restrict__ ctx, float* __restrict__ alpha)
{
    int bt = blockIdx.x;            // 0 .. B*T-1
    int b = bt / TT;
    int idx = bt % TT;
    int t = (idx < 256) ? idx : 767 - idx;   // bijective, load-balancing
    int btr = b * TT + t;
    int tid = threadIdx.x;          // 0..511

    __shared__ float eq_sh[HH];
    __shared__ float v2_sh[HH];
    __shared__ float al_sh[TT];
    __shared__ float red[8];
    __shared__ float4 cred[8][64];

    if (tid < HH) {
        eq_sh[tid] = Eq[btr * HH + tid];
        v2_sh[tid] = -2.0f * v[tid];
    }
    __syncthreads();

    const float4* q4p = reinterpret_cast<const float4*>(eq_sh);
    const float4* v4p = reinterpret_cast<const float4*>(v2_sh);

    // ---- score for s = tid (one per thread, coalesced EkT loads) ----
    float sc = -3.0e38f;
    if (tid <= t) {
        const float4* ek = reinterpret_cast<const float4*>(EkT) + (b * TT + tid);
        float a = 0.f;
#pragma unroll 4
        for (int h4 = 0; h4 < HH / 4; ++h4) {
            float4 e4 = ek[h4 * NBT];     // lanes contiguous: 1KB/wave
            float4 q4 = q4p[h4];          // broadcast
            float4 vv = v4p[h4];          // broadcast
            float r0 = __builtin_amdgcn_rcpf(__builtin_fmaf(q4.x, e4.x, 1.0f));
            float r1 = __builtin_amdgcn_rcpf(__builtin_fmaf(q4.y, e4.y, 1.0f));
            float r2 = __builtin_amdgcn_rcpf(__builtin_fmaf(q4.z, e4.z, 1.0f));
            float r3 = __builtin_amdgcn_rcpf(__builtin_fmaf(q4.w, e4.w, 1.0f));
            a = __builtin_fmaf(vv.x, r0, a);
            a = __builtin_fmaf(vv.y, r1, a);
            a = __builtin_fmaf(vv.z, r2, a);
            a = __builtin_fmaf(vv.w, r3, a);
        }
        sc = a;
    }

    // ---- block max (8 waves) ----
    float m = sc;
#pragma unroll
    for (int off = 32; off > 0; off >>= 1)
        m = fmaxf(m, __shfl_xor(m, off));
    int wid = tid >> 6;
    if ((tid & 63) == 0) red[wid] = m;
    __syncthreads();
    m = fmaxf(fmaxf(fmaxf(red[0], red[1]), fmaxf(red[2], red[3])),
              fmaxf(fmaxf(red[4], red[5]), fmaxf(red[6], red[7])));

    // ---- exp + block sum ----
    const float LOG2E = 1.4426950408889634f;
    float e = (tid <= t) ? __builtin_amdgcn_exp2f((sc - m) * LOG2E) : 0.f;
    float ssum = e;
#pragma unroll
    for (int off = 32; off > 0; off >>= 1)
        ssum += __shfl_xor(ssum, off);
    __syncthreads();           // everyone done reading red[]
    if ((tid & 63) == 0) red[wid] = ssum;
    __syncthreads();
    float denom = (red[0] + red[1]) + (red[2] + red[3])
                + (red[4] + red[5]) + (red[6] + red[7]);
    float a0 = e * __builtin_amdgcn_rcpf(denom);

    al_sh[tid] = a0;
    alpha[btr * TT + tid] = a0;
    __syncthreads();

    // ---- context: thread = (h-group hc, s-group sg) ----
    // hc in [0,64): channels 4hc..4hc+3; sg in [0,8): s = sg, sg+8, ...
    int hc = tid & 63;
    int sg = tid >> 6;
    const float4* kb4 = reinterpret_cast<const float4*>(Kraw + b * TT * HH) + hc;
    float4 acc4 = {0.f, 0.f, 0.f, 0.f};
#pragma unroll 2
    for (int s = sg; s <= t; s += 8) {
        float4 k4 = kb4[s * 64];            // coalesced 1KB/wave
        float  al = al_sh[s];               // wave-uniform broadcast
        acc4.x = __builtin_fmaf(al, k4.x, acc4.x);
        acc4.y = __builtin_fmaf(al, k4.y, acc4.y);
        acc4.z = __builtin_fmaf(al, k4.z, acc4.z);
        acc4.w = __builtin_fmaf(al, k4.w, acc4.w);
    }
    cred[sg][hc] = acc4;
    __syncthreads();
    if (sg == 0) {
        float4 out = {0.f, 0.f, 0.f, 0.f};
#pragma unroll
        for (int g = 0; g < 8; ++g) {
            float4 c = cred[g][hc];
            out.x += c.x; out.y += c.y; out.z += c.z; out.w += c.w;
        }
        reinterpret_cast<float4*>(ctx + btr * HH)[hc] = out;
    }
}

extern "C" void kernel_launch(void* const* d_in, const int* in_sizes, int n_in,
                              void* d_out, int out_size, void* d_ws, size_t ws_size,
                              hipStream_t stream) {
    const float* Q  = (const float*)d_in[0];
    const float* K  = (const float*)d_in[1];
    const float* Wq = (const float*)d_in[2];
    const float* Wk = (const float*)d_in[3];
    const float* v  = (const float*)d_in[4];

    float* ctx   = (float*)d_out;                      // B*T*H floats
    float* alpha = (float*)d_out + BB * TT * HH;       // B*T*T floats

    float* Eq  = (float*)d_ws;                         // B*T*H
    float* EkT = Eq + BB * TT * HH;                    // B*T*H (packed-transposed)

    proj_kernel<<<2 * NBT / 8, 256, 0, stream>>>(Q, K, Wq, Wk, Eq, EkT);
    attn_kernel<<<NBT, 512, 0, stream>>>(Eq, EkT, K, v, ctx, alpha);
}